// Round 5
// baseline (333.054 us; speedup 1.0000x reference)
//
#include <hip/hip_runtime.h>
#include <hip/hip_cooperative_groups.h>
#include <math.h>

namespace cg = cooperative_groups;

#define BB 2
#define TT 8
#define NN 512
#define HH 64
#define NC 10

typedef unsigned char uchar;

__device__ __forceinline__ float elu1(float v){ return v > 0.f ? v : expm1f(v); }
__device__ __forceinline__ float sigm(float v){ return 1.f/(1.f+expf(-v)); }

struct Prm {
    const float *x_seq, *sadj, *dynW, *lamp;
    const float *g1_Wl, *g1_Wr, *g1_att, *g1_b;
    const float *g2_Wl, *g2_Wr, *g2_att, *g2_b;
    const float *Wih0, *Whh0, *bih0, *bhh0;
    const float *Wih1, *Whh1, *bih1, *bhh1;
    const float *attnW, *attnb, *W1, *b1, *lng, *lnb, *W2, *b2;
    uchar *M0, *M1;
    float *AB, *ui, *vj, *xl2, *xr2, *hseq;
    float4 *WT4;                   // [m][k*64+gg], m=0:Whh0, m=1:Whh1 (k-major)
    float *out;
};

union __align__(16) SharedU {
    struct { float tr[64][65]; } p0;
    struct { float x_s[NN]; float Wl2[64*64]; float Wr2[64*64];
             float S_s[8][4]; float h_s[8][HH]; } p1;
    struct { float xl_s[256][68]; float wT_s[256][36];
             float v_s[256]; float z_s[32]; } p2;                 // 107648 B
    struct { float gi[BB*TT*192]; float hs[BB*TT*HH]; float y[BB*TT*HH];
             float h_lds[BB][HH]; float part[BB][2][3][HH];
             float sc[BB][TT]; float at[BB][TT];
             float fin[BB][HH]; float z[BB][HH]; float g[BB][HH];
             float mu[BB]; float iv[BB]; } p3;
};

__global__ __launch_bounds__(512) void k_fused(Prm p)
{
    __shared__ SharedU sh;
    cg::grid_group grid = cg::this_grid();
    int bid = blockIdx.x, tid = threadIdx.x;

    // ================= Phase 0: masks, WT4 (k-major), hseq=0, AB =============
    if (bid < 64){
        int by = bid >> 3, bx = bid & 7;
        int i0 = by*64, j0 = bx*64;
        #pragma unroll
        for (int q = 0; q < 2; ++q){
            int idx = q*512 + tid;
            int r = idx >> 4, c4 = idx & 15;
            float4 v = *(const float4*)&p.dynW[(size_t)(j0+r)*NN + i0 + 4*c4];
            sh.p0.tr[r][4*c4+0] = v.x; sh.p0.tr[r][4*c4+1] = v.y;
            sh.p0.tr[r][4*c4+2] = v.z; sh.p0.tr[r][4*c4+3] = v.w;
        }
        __syncthreads();
        #pragma unroll
        for (int q = 0; q < 2; ++q){
            int idx = q*512 + tid;
            int row = idx >> 4, c4 = idx & 15;
            int i = i0 + row, j = j0 + 4*c4;
            float4 d  = *(const float4*)&p.dynW[(size_t)i*NN + j];
            float4 sa = *(const float4*)&p.sadj[(size_t)i*NN + j];
            uchar4 m0, m1;
            float dd0 = d.x + sh.p0.tr[4*c4+0][row];
            float dd1 = d.y + sh.p0.tr[4*c4+1][row];
            float dd2 = d.z + sh.p0.tr[4*c4+2][row];
            float dd3 = d.w + sh.p0.tr[4*c4+3][row];
            m0.x = (sa.x > 0.f) || (i == j+0);
            m0.y = (sa.y > 0.f) || (i == j+1);
            m0.z = (sa.z > 0.f) || (i == j+2);
            m0.w = (sa.w > 0.f) || (i == j+3);
            m1.x = m0.x || (dd0 > 0.f);
            m1.y = m0.y || (dd1 > 0.f);
            m1.z = m0.z || (dd2 > 0.f);
            m1.w = m0.w || (dd3 > 0.f);
            *(uchar4*)&p.M0[(size_t)i*NN + j] = m0;
            *(uchar4*)&p.M1[(size_t)i*NN + j] = m1;
        }
    } else if (bid < 80){
        int idx = (bid - 64)*512 + tid;          // 0..8191
        int m = idx >> 12, r = idx & 4095;
        int k = r >> 6, gg = r & 63;
        const float* W = m ? p.Whh1 : p.Whh0;
        float4 o;
        o.x = W[k*192 + gg];
        o.y = W[k*192 + 64 + gg];
        o.z = W[k*192 + 128 + gg];
        o.w = 0.f;
        p.WT4[(size_t)m*4096 + r] = o;           // [m][k*64+gg]
    } else if (bid == 80){
        p.hseq[tid] = 0.f;
        p.hseq[512 + tid] = 0.f;
    } else if (bid == 81){
        if (tid < 8){
            int h = tid & 3;
            const float* W = (tid < 4) ? p.g1_Wr : p.g1_Wl;
            float s = 0.f;
            for (int c = 0; c < 16; ++c) s += p.g1_att[h*16+c]*W[h*16+c];
            p.AB[tid] = s;
        }
    }
    grid.sync();

    // ================= Phase 1: GAT1 + lin2 (8 nodes/block, wave-per-node) ===
    {
        #pragma unroll
        for (int q = 0; q < 2; ++q){
            int idx = q*512 + tid;
            ((float4*)sh.p1.Wl2)[idx] = ((const float4*)p.g2_Wl)[idx];
            ((float4*)sh.p1.Wr2)[idx] = ((const float4*)p.g2_Wr)[idx];
        }
        int w = tid >> 6, jl = tid & 63;
        for (int s = 0; s < 4; ++s){
            int vb = bid*4 + s;                  // 0..1023
            int bt = vb >> 6, it = vb & 63;
            int i0v = it*8;
            int t = bt & 7;
            const uchar* M = t ? p.M1 : p.M0;
            __syncthreads();                     // protect x_s/h_s reuse (+Wl2 1st iter)
            sh.p1.x_s[tid] = p.x_seq[bt*NN + tid];
            __syncthreads();
            int i = i0v + w;
            float xi = sh.p1.x_s[i];
            const uchar* Mrow = M + (size_t)i*NN;
            float xj[8], msk[8];
            #pragma unroll
            for (int jj = 0; jj < 8; ++jj){
                int j = jj*64 + jl;
                xj[jj] = sh.p1.x_s[j];
                msk[jj] = Mrow[j] ? 1.f : 0.f;
            }
            float sw[4] = {0,0,0,0}, swx[4] = {0,0,0,0};
            for (int h = 0; h < 4; ++h){
                float acc[8] = {0,0,0,0,0,0,0,0};
                #pragma unroll
                for (int c = 0; c < 16; ++c){
                    int hc = h*16 + c;
                    float wl = p.g1_Wl[hc];
                    float q  = 0.4f * p.g1_att[hc];
                    float pr = xi * p.g1_Wr[hc];
                    #pragma unroll
                    for (int jj = 0; jj < 8; ++jj){
                        float sv = fmaf(xj[jj], wl, pr);
                        acc[jj] = fmaf(q, fabsf(sv), acc[jj]);
                    }
                }
                float lin = 0.6f * xi * p.AB[h];
                float al6 = 0.6f * p.AB[4+h];
                #pragma unroll
                for (int jj = 0; jj < 8; ++jj){
                    float e = acc[jj] + fmaf(al6, xj[jj], lin);
                    float ww = msk[jj] * __expf(e);
                    sw[h] += ww;
                    swx[h] = fmaf(ww, xj[jj], swx[h]);
                }
            }
            #pragma unroll
            for (int off = 32; off; off >>= 1){
                #pragma unroll
                for (int h = 0; h < 4; ++h){
                    sw[h]  += __shfl_down(sw[h],  off);
                    swx[h] += __shfl_down(swx[h], off);
                }
            }
            if (jl == 0){
                #pragma unroll
                for (int h = 0; h < 4; ++h) sh.p1.S_s[w][h] = swx[h] / sw[h];
            }
            __syncthreads();
            {
                int hc = tid & 63, row = tid >> 6;
                float v = sh.p1.S_s[row][hc >> 4] * p.g1_Wl[hc] + p.g1_b[hc];
                sh.p1.h_s[row][hc] = elu1(v);
            }
            __syncthreads();
            {
                int c = tid & 63, row = tid >> 6;
                float al = 0.f, ar = 0.f;
                #pragma unroll 8
                for (int k = 0; k < 64; ++k){
                    float hv = sh.p1.h_s[row][k];
                    al = fmaf(hv, sh.p1.Wl2[k*64 + c], al);
                    ar = fmaf(hv, sh.p1.Wr2[k*64 + c], ar);
                }
                size_t ridx = (size_t)(bt*NN + i0v + row);
                p.xl2[ridx*HH + c] = al;
                p.xr2[ridx*HH + c] = ar;
                float a2 = p.g2_att[c];
                float pu = a2 * ar, pv = a2 * al;
                #pragma unroll
                for (int off = 32; off; off >>= 1){
                    pu += __shfl_down(pu, off);
                    pv += __shfl_down(pv, off);
                }
                if (c == 0){ p.ui[ridx] = pu; p.vj[ridx] = pv; }
            }
        }
    }
    grid.sync();

    // ================= Phase 2: flash GAT2 (proven 8-wave structure) =========
    {
        int bt = bid >> 4, t = bt & 7;
        int i0 = (bid & 15) * 32;
        int base = bt * NN;
        const uchar* M = t ? p.M1 : p.M0;

        int ig = __builtin_amdgcn_readfirstlane(tid >> 6);
        int jg = tid & 63;
        int ln = jg;
        int ig2 = ln >> 3, cg2 = ln & 7;

        const float* xrp0 = p.xr2 + (size_t)(base + i0 + ig*4 + 0)*HH;
        const float* xrp1 = p.xr2 + (size_t)(base + i0 + ig*4 + 1)*HH;
        const float* xrp2 = p.xr2 + (size_t)(base + i0 + ig*4 + 2)*HH;
        const float* xrp3 = p.xr2 + (size_t)(base + i0 + ig*4 + 3)*HH;
        float u0 = 0.6f*p.ui[base + i0 + ig*4 + 0];
        float u1 = 0.6f*p.ui[base + i0 + ig*4 + 1];
        float u2 = 0.6f*p.ui[base + i0 + ig*4 + 2];
        float u3 = 0.6f*p.ui[base + i0 + ig*4 + 3];

        float zreg[4] = {0.f,0.f,0.f,0.f};
        float acc[4][8];
        #pragma unroll
        for (int a = 0; a < 4; ++a)
            #pragma unroll
            for (int r = 0; r < 8; ++r) acc[a][r] = 0.f;

        for (int tile = 0; tile < 2; ++tile){
            int j0 = tile * 256;
            __syncthreads();
            #pragma unroll
            for (int q = 0; q < 8; ++q){
                int idx = q*512 + tid;
                int row = idx >> 4, c4 = idx & 15;
                ((float4*)&sh.p2.xl_s[row][0])[c4] =
                    ((const float4*)&p.xl2[(size_t)(base+j0+row)*HH])[c4];
            }
            if (tid < 256) sh.p2.v_s[tid] = p.vj[base + j0 + tid];
            __syncthreads();
            float e[4][4];
            #pragma unroll
            for (int jj = 0; jj < 4; ++jj){
                float vv = 0.6f * sh.p2.v_s[jj*64 + jg];
                e[0][jj] = u0 + vv; e[1][jj] = u1 + vv;
                e[2][jj] = u2 + vv; e[3][jj] = u3 + vv;
            }
            #pragma unroll 4
            for (int c4 = 0; c4 < 16; ++c4){
                float4 a4 = *(const float4*)&p.g2_att[c4*4];
                float qk[4];
                qk[0] = 0.4f*a4.x; qk[1] = 0.4f*a4.y; qk[2] = 0.4f*a4.z; qk[3] = 0.4f*a4.w;
                float rr[4][4];
                *(float4*)rr[0] = *(const float4*)&xrp0[c4*4];
                *(float4*)rr[1] = *(const float4*)&xrp1[c4*4];
                *(float4*)rr[2] = *(const float4*)&xrp2[c4*4];
                *(float4*)rr[3] = *(const float4*)&xrp3[c4*4];
                float xlv[4][4];
                #pragma unroll
                for (int jj = 0; jj < 4; ++jj)
                    *(float4*)xlv[jj] = ((const float4*)&sh.p2.xl_s[jj*64+jg][0])[c4];
                #pragma unroll
                for (int jj = 0; jj < 4; ++jj)
                    #pragma unroll
                    for (int k = 0; k < 4; ++k){
                        float xc = xlv[jj][k];
                        #pragma unroll
                        for (int ii = 0; ii < 4; ++ii)
                            e[ii][jj] = fmaf(qk[k], fabsf(rr[ii][k] + xc), e[ii][jj]);
                    }
            }
            #pragma unroll
            for (int jj = 0; jj < 4; ++jj){
                int j = jj*64 + jg;
                const uchar* mp = &M[(size_t)(i0 + ig*4)*NN + j0 + j];
                float w0 = mp[0]      ? __expf(e[0][jj]) : 0.f;
                float w1 = mp[NN]     ? __expf(e[1][jj]) : 0.f;
                float w2 = mp[2*NN]   ? __expf(e[2][jj]) : 0.f;
                float w3 = mp[3*NN]   ? __expf(e[3][jj]) : 0.f;
                zreg[0] += w0; zreg[1] += w1; zreg[2] += w2; zreg[3] += w3;
                float4 wq; wq.x = w0; wq.y = w1; wq.z = w2; wq.w = w3;
                *(float4*)&sh.p2.wT_s[j][ig*4] = wq;
            }
            __syncthreads();
            #pragma unroll 4
            for (int jj = 0; jj < 32; ++jj){
                int j = ig*32 + jj;
                float w4[4], xa[8];
                *(float4*)w4      = *(const float4*)&sh.p2.wT_s[j][ig2*4];
                *(float4*)&xa[0]  = ((const float4*)&sh.p2.xl_s[j][0])[cg2*2+0];
                *(float4*)&xa[4]  = ((const float4*)&sh.p2.xl_s[j][0])[cg2*2+1];
                #pragma unroll
                for (int a = 0; a < 4; ++a)
                    #pragma unroll
                    for (int r = 0; r < 8; ++r)
                        acc[a][r] = fmaf(w4[a], xa[r], acc[a][r]);
            }
        }
        __syncthreads();
        #pragma unroll
        for (int off = 32; off; off >>= 1){
            #pragma unroll
            for (int ii = 0; ii < 4; ++ii) zreg[ii] += __shfl_down(zreg[ii], off);
        }
        if (jg == 0){
            #pragma unroll
            for (int ii = 0; ii < 4; ++ii) sh.p2.z_s[ig*4+ii] = zreg[ii];
        }
        float* scratch = &sh.p2.xl_s[0][0];     // 32*448 = 14336 floats < 17408
        if (ig > 0){
            #pragma unroll
            for (int a = 0; a < 4; ++a)
                #pragma unroll
                for (int r = 0; r < 8; ++r)
                    scratch[(a*8+r)*448 + (ig-1)*64 + ln] = acc[a][r];
        }
        __syncthreads();
        if (ig == 0){
            float pm[8];
            #pragma unroll
            for (int r = 0; r < 8; ++r) pm[r] = 0.f;
            #pragma unroll
            for (int a = 0; a < 4; ++a){
                float rz = 1.f / sh.p2.z_s[ig2*4 + a];
                #pragma unroll
                for (int r = 0; r < 8; ++r){
                    float s = acc[a][r];
                    #pragma unroll
                    for (int w = 0; w < 7; ++w)
                        s += scratch[(a*8+r)*448 + w*64 + ln];
                    float h = elu1(s*rz + p.g2_b[cg2*8 + r]);
                    pm[r] += h;
                }
            }
            #pragma unroll
            for (int off = 32; off >= 8; off >>= 1){
                #pragma unroll
                for (int r = 0; r < 8; ++r) pm[r] += __shfl_down(pm[r], off);
            }
            if (ig2 == 0){
                #pragma unroll
                for (int r = 0; r < 8; ++r)
                    atomicAdd(&p.hseq[bt*HH + cg2*8 + r], pm[r] * (1.f/(float)NN));
            }
        }
    }
    grid.sync();

    // ================= Phase 3: GRU x2 + head (block 0 only) =================
    if (bid != 0) return;
    {
        int wave = tid >> 6, lane = tid & 63;
        int gb = wave >> 1, half = wave & 1;
        bool gruw = (wave < 4);

        float4 Wreg[32];
        if (gruw){
            const float4* src = p.WT4;           // layer 0, [k*64+gg]
            #pragma unroll
            for (int kk = 0; kk < 32; ++kk)
                Wreg[kk] = src[(size_t)(half*32 + kk)*64 + lane];
        }
        for (int v = tid; v < BB*TT*HH; v += 512) sh.p3.hs[v] = p.hseq[v];
        if (tid < BB*HH) sh.p3.h_lds[tid >> 6][tid & 63] = 0.f;
        __syncthreads();
        #pragma unroll
        for (int o = 0; o < 6; ++o){
            int idx = o*512 + tid;
            int b = idx / 192, g = idx % 192;
            float a = p.bih0[g];
            const float* hr = &sh.p3.hs[b*HH];
            #pragma unroll 8
            for (int k = 0; k < HH; ++k) a = fmaf(hr[k], p.Wih0[k*192 + g], a);
            sh.p3.gi[idx] = a;
        }
        __syncthreads();
        // ---- layer 0 ----
        {
            float bhr = 0.f, bhz = 0.f, bhn = 0.f;
            if (gruw && half == 0){ bhr = p.bhh0[lane]; bhz = p.bhh0[64+lane]; bhn = p.bhh0[128+lane]; }
            for (int t = 0; t < TT; ++t){
                if (gruw){
                    float hh[32];
                    #pragma unroll
                    for (int q = 0; q < 8; ++q)
                        *(float4*)&hh[q*4] = *(const float4*)&sh.p3.h_lds[gb][half*32 + q*4];
                    float ar0=0,ar1=0,az0=0,az1=0,an0=0,an1=0;
                    #pragma unroll
                    for (int kk = 0; kk < 32; kk += 2){
                        ar0 = fmaf(Wreg[kk].x,   hh[kk],   ar0);
                        az0 = fmaf(Wreg[kk].y,   hh[kk],   az0);
                        an0 = fmaf(Wreg[kk].z,   hh[kk],   an0);
                        ar1 = fmaf(Wreg[kk+1].x, hh[kk+1], ar1);
                        az1 = fmaf(Wreg[kk+1].y, hh[kk+1], az1);
                        an1 = fmaf(Wreg[kk+1].z, hh[kk+1], an1);
                    }
                    sh.p3.part[gb][half][0][lane] = ar0 + ar1;
                    sh.p3.part[gb][half][1][lane] = az0 + az1;
                    sh.p3.part[gb][half][2][lane] = an0 + an1;
                }
                __syncthreads();
                if (gruw && half == 0){
                    float ghr = sh.p3.part[gb][0][0][lane] + sh.p3.part[gb][1][0][lane] + bhr;
                    float ghz = sh.p3.part[gb][0][1][lane] + sh.p3.part[gb][1][1][lane] + bhz;
                    float ghn = sh.p3.part[gb][0][2][lane] + sh.p3.part[gb][1][2][lane] + bhn;
                    const float* gi = &sh.p3.gi[(gb*TT + t)*192];
                    float r = sigm(gi[lane] + ghr);
                    float z = sigm(gi[64+lane] + ghz);
                    float n = tanhf(gi[128+lane] + r*ghn);
                    float hn = (1.f - z)*n + z*sh.p3.h_lds[gb][lane];
                    sh.p3.h_lds[gb][lane] = hn;
                    sh.p3.y[(gb*TT + t)*HH + lane] = hn;
                }
                __syncthreads();
            }
        }
        if (gruw){
            const float4* src = p.WT4 + 4096;    // layer 1
            #pragma unroll
            for (int kk = 0; kk < 32; ++kk)
                Wreg[kk] = src[(size_t)(half*32 + kk)*64 + lane];
        }
        #pragma unroll
        for (int o = 0; o < 6; ++o){
            int idx = o*512 + tid;
            int b = idx / 192, g = idx % 192;
            float a = p.bih1[g];
            const float* yr = &sh.p3.y[b*HH];
            #pragma unroll 8
            for (int k = 0; k < HH; ++k) a = fmaf(yr[k], p.Wih1[k*192 + g], a);
            sh.p3.gi[idx] = a;
        }
        if (tid < BB*HH) sh.p3.h_lds[tid >> 6][tid & 63] = 0.f;
        __syncthreads();
        // ---- layer 1 ----
        {
            float bhr = 0.f, bhz = 0.f, bhn = 0.f;
            if (gruw && half == 0){ bhr = p.bhh1[lane]; bhz = p.bhh1[64+lane]; bhn = p.bhh1[128+lane]; }
            for (int t = 0; t < TT; ++t){
                if (gruw){
                    float hh[32];
                    #pragma unroll
                    for (int q = 0; q < 8; ++q)
                        *(float4*)&hh[q*4] = *(const float4*)&sh.p3.h_lds[gb][half*32 + q*4];
                    float ar0=0,ar1=0,az0=0,az1=0,an0=0,an1=0;
                    #pragma unroll
                    for (int kk = 0; kk < 32; kk += 2){
                        ar0 = fmaf(Wreg[kk].x,   hh[kk],   ar0);
                        az0 = fmaf(Wreg[kk].y,   hh[kk],   az0);
                        an0 = fmaf(Wreg[kk].z,   hh[kk],   an0);
                        ar1 = fmaf(Wreg[kk+1].x, hh[kk+1], ar1);
                        az1 = fmaf(Wreg[kk+1].y, hh[kk+1], az1);
                        an1 = fmaf(Wreg[kk+1].z, hh[kk+1], an1);
                    }
                    sh.p3.part[gb][half][0][lane] = ar0 + ar1;
                    sh.p3.part[gb][half][1][lane] = az0 + az1;
                    sh.p3.part[gb][half][2][lane] = an0 + an1;
                }
                __syncthreads();
                if (gruw && half == 0){
                    float ghr = sh.p3.part[gb][0][0][lane] + sh.p3.part[gb][1][0][lane] + bhr;
                    float ghz = sh.p3.part[gb][0][1][lane] + sh.p3.part[gb][1][1][lane] + bhz;
                    float ghn = sh.p3.part[gb][0][2][lane] + sh.p3.part[gb][1][2][lane] + bhn;
                    const float* gi = &sh.p3.gi[(gb*TT + t)*192];
                    float r = sigm(gi[lane] + ghr);
                    float z = sigm(gi[64+lane] + ghz);
                    float n = tanhf(gi[128+lane] + r*ghn);
                    float hn = (1.f - z)*n + z*sh.p3.h_lds[gb][lane];
                    sh.p3.h_lds[gb][lane] = hn;
                    sh.p3.y[(gb*TT + t)*HH + lane] = hn;
                }
                __syncthreads();
            }
        }
        // ---- head ----
        float lam = fmaxf(p.lamp[0], 0.01f);
        if (tid < TT) p.out[BB*NC + tid] = expf(-lam*(float)tid);
        if (tid < BB*TT){
            int bb = tid >> 3, t = tid & 7;
            float s = p.attnb[0];
            const float* r = &sh.p3.y[(bb*TT+t)*HH];
            for (int h = 0; h < HH; ++h) s += r[h]*p.attnW[h];
            sh.p3.sc[bb][t] = s;
        }
        __syncthreads();
        if (tid < BB){
            float mx = -INFINITY;
            for (int t = 0; t < TT; ++t) mx = fmaxf(mx, sh.p3.sc[tid][t]);
            float se = 0.f;
            for (int t = 0; t < TT; ++t){ float w = expf(sh.p3.sc[tid][t]-mx); sh.p3.at[tid][t] = w; se += w; }
            for (int t = 0; t < TT; ++t){
                sh.p3.at[tid][t] /= se;
                p.out[BB*NC + TT + tid*TT + t] = sh.p3.at[tid][t];
            }
        }
        __syncthreads();
        if (tid < BB*HH){
            int bb = tid >> 6, h = tid & 63;
            float a = 0.f;
            for (int t = 0; t < TT; ++t) a += sh.p3.at[bb][t]*sh.p3.y[(bb*TT+t)*HH + h];
            sh.p3.fin[bb][h] = a;
        }
        __syncthreads();
        if (tid < BB*HH){
            int bb = tid >> 6, h = tid & 63;
            float a = p.b1[h];
            for (int k = 0; k < HH; ++k) a += sh.p3.fin[bb][k]*p.W1[k*HH+h];
            sh.p3.z[bb][h] = a;
        }
        __syncthreads();
        if (tid < BB){
            float mu = 0.f;
            for (int h = 0; h < HH; ++h) mu += sh.p3.z[tid][h];
            mu *= (1.f/HH);
            float v = 0.f;
            for (int h = 0; h < HH; ++h){ float d = sh.p3.z[tid][h]-mu; v += d*d; }
            v *= (1.f/HH);
            sh.p3.mu[tid] = mu; sh.p3.iv[tid] = 1.f/sqrtf(v + 1e-5f);
        }
        __syncthreads();
        if (tid < BB*HH){
            int bb = tid >> 6, h = tid & 63;
            float zn = (sh.p3.z[bb][h]-sh.p3.mu[bb])*sh.p3.iv[bb]*p.lng[h] + p.lnb[h];
            sh.p3.g[bb][h] = 0.5f*zn*(1.f + erff(zn*0.70710678118654752f));
        }
        __syncthreads();
        if (tid < BB*NC){
            int bb = tid / NC, c = tid % NC;
            float a = p.b2[c];
            for (int k = 0; k < HH; ++k) a += sh.p3.g[bb][k]*p.W2[k*NC+c];
            p.out[bb*NC + c] = a;
        }
    }
}

extern "C" void kernel_launch(void* const* d_in, const int* in_sizes, int n_in,
                              void* d_out, int out_size, void* d_ws, size_t ws_size,
                              hipStream_t stream)
{
    Prm p;
    p.x_seq = (const float*)d_in[0];
    p.sadj  = (const float*)d_in[1];
    p.dynW  = (const float*)d_in[2];
    p.lamp  = (const float*)d_in[3];
    p.g1_Wl = (const float*)d_in[4];
    p.g1_Wr = (const float*)d_in[5];
    p.g1_att= (const float*)d_in[6];
    p.g1_b  = (const float*)d_in[7];
    p.g2_Wl = (const float*)d_in[8];
    p.g2_Wr = (const float*)d_in[9];
    p.g2_att= (const float*)d_in[10];
    p.g2_b  = (const float*)d_in[11];
    p.Wih0  = (const float*)d_in[12];
    p.Whh0  = (const float*)d_in[13];
    p.bih0  = (const float*)d_in[14];
    p.bhh0  = (const float*)d_in[15];
    p.Wih1  = (const float*)d_in[16];
    p.Whh1  = (const float*)d_in[17];
    p.bih1  = (const float*)d_in[18];
    p.bhh1  = (const float*)d_in[19];
    p.attnW = (const float*)d_in[20];
    p.attnb = (const float*)d_in[21];
    p.W1    = (const float*)d_in[22];
    p.b1    = (const float*)d_in[23];
    p.lng   = (const float*)d_in[24];
    p.lnb   = (const float*)d_in[25];
    p.W2    = (const float*)d_in[26];
    p.b2    = (const float*)d_in[27];
    p.out   = (float*)d_out;

    const int RWS = BB*TT*NN*HH;                  // 524288
    p.M0 = (uchar*)d_ws;                          // 262144 B
    p.M1 = p.M0 + (size_t)NN*NN;                  // 262144 B
    float* fb = (float*)(p.M1 + (size_t)NN*NN);
    p.AB   = fb;                                  // 16
    p.ui   = p.AB   + 16;                         // 8192
    p.vj   = p.ui   + BB*TT*NN;                   // 8192
    p.xl2  = p.vj   + BB*TT*NN;                   // 524288
    p.xr2  = p.xl2  + RWS;                        // 524288
    p.hseq = p.xr2  + RWS;                        // 1024
    p.WT4  = (float4*)(p.hseq + BB*TT*HH);        // 2*4096 float4 = 131072 B

    void* args[] = { &p };
    hipLaunchCooperativeKernel((const void*)k_fused, dim3(256), dim3(512),
                               args, 0, stream);
}